// Round 1
// baseline (114.096 us; speedup 1.0000x reference)
//
#include <hip/hip_runtime.h>

#define BLOCK 8
#define NGRID 512

// Compile-time replication of:
//   np.random.RandomState(0).choice(np.array([1.0,3.0],f32), size=(512,8))
// RandomState scalar seeding == init_genrand(0); randint(0,2) legacy bounded
// path: one 32-bit MT draw per value, value = draw & 1.
// Rows deduplicated (first-occurrence order kept): under strict-> argmax a
// duplicate row can never win, so pruning is bitwise-identical to scanning
// all 512 rows in order.
struct Tabs {
  float g[NGRID][BLOCK];   // distinct rows, first-occurrence order
  float norm[NGRID];       // 8*(1+popcount)  (exact in f32)
  double dinv[NGRID];      // fl64(1/norm): (float)((double)x*dinv) == fl32(x/norm)
  int nd;                  // number of distinct rows
};

constexpr Tabs make_tabs() {
  Tabs t{};
  // MT19937 state, numpy legacy seeding with seed=0
  unsigned mt[624] = {};
  {
    unsigned s = 0u;
    for (int i = 0; i < 624; ++i) {
      mt[i] = s;
      s = 1812433253u * (s ^ (s >> 30)) + (unsigned)(i + 1);
    }
  }
  int pos = 624;
  unsigned char rows[NGRID] = {};
  for (int j = 0; j < NGRID; ++j) {
    unsigned char bits = 0;
    for (int i = 0; i < BLOCK; ++i) {
      if (pos == 624) {
        for (int k = 0; k < 624; ++k) {
          int k1 = (k + 1 < 624) ? k + 1 : 0;
          int k397 = (k + 397 < 624) ? k + 397 : k + 397 - 624;
          unsigned y = (mt[k] & 0x80000000u) | (mt[k1] & 0x7fffffffu);
          unsigned v = mt[k397] ^ (y >> 1);
          if (y & 1u) v ^= 0x9908b0dfu;
          mt[k] = v;
        }
        pos = 0;
      }
      unsigned y = mt[pos++];
      y ^= y >> 11;
      y ^= (y << 7) & 0x9d2c5680u;
      y ^= (y << 15) & 0xefc60000u;
      y ^= y >> 18;
      if (y & 1u) bits |= (unsigned char)(1u << i);
    }
    rows[j] = bits;
  }
  // dedup via 256-entry first-seen table (cheap on constexpr steps)
  short first[256];
  for (int i = 0; i < 256; ++i) first[i] = -1;
  int nd = 0;
  for (int j = 0; j < NGRID; ++j) {
    unsigned b = rows[j];
    if (first[b] < 0) {
      first[b] = (short)nd;
      int pop = 0;
      for (int i = 0; i < BLOCK; ++i) {
        int bit = (int)((b >> i) & 1u);
        t.g[nd][i] = bit ? 3.0f : 1.0f;
        pop += bit;
      }
      int n = 8 + 8 * pop;
      t.norm[nd] = (float)n;
      t.dinv[nd] = 1.0 / (double)n;
      ++nd;
    }
  }
  t.nd = nd;
  return t;
}

constexpr Tabs TABS = make_tabs();
constexpr int ND = TABS.nd;
static_assert(ND > 0 && ND <= NGRID, "dedup sanity");

__constant__ Tabs c_tabs = TABS;

__global__ __launch_bounds__(256) void _IQ2XSQuantWeight_12945031430379_kernel(
    const float* __restrict__ w, float* __restrict__ out, int nb) {
  int t = blockIdx.x * blockDim.x + threadIdx.x;
  if (t >= nb) return;

  const float4* wp = reinterpret_cast<const float4*>(w) + (size_t)2 * t;
  float4 w0 = wp[0];
  float4 w1 = wp[1];
  float wv[BLOCK] = {w0.x, w0.y, w0.z, w0.w, w1.x, w1.y, w1.z, w1.w};

  float a[BLOCK];
#pragma unroll
  for (int i = 0; i < BLOCK; ++i) a[i] = __builtin_fabsf(wv[i]);

  // Score scan: dot = ascending-k fma chain (sgemm order); square = lone f32
  // mul; division via exact f64-reciprocal trick == fl32(dd/norm). Strict >
  // with ascending k replicates np.argmax first-max semantics exactly.
  float best = -1.0f;
  int bestk = 0;
#pragma unroll 4
  for (int k = 0; k < ND; ++k) {
    float d = 0.0f;
#pragma unroll
    for (int i = 0; i < BLOCK; ++i) d = __builtin_fmaf(a[i], c_tabs.g[k][i], d);
    float dd = d * d;
    float sc = (float)((double)dd * c_tabs.dinv[k]);
    bool gt = sc > best;
    best = gt ? sc : best;
    bestk = gt ? k : bestk;
  }

  // Epilogue: replicate numpy ordering.
  float q[BLOCK];
#pragma unroll
  for (int i = 0; i < BLOCK; ++i) q[i] = c_tabs.g[bestk][i];  // divergent gather, L1-resident

  float p[BLOCK];
#pragma unroll
  for (int i = 0; i < BLOCK; ++i) p[i] = a[i] * q[i];
  // numpy pairwise sum for n==8: ((p0+p1)+(p2+p3))+((p4+p5)+(p6+p7))
  float num = ((p[0] + p[1]) + (p[2] + p[3])) + ((p[4] + p[5]) + (p[6] + p[7]));
  float scale = num / c_tabs.norm[bestk];  // IEEE f32 divide, once per block

  float o[BLOCK];
#pragma unroll
  for (int i = 0; i < BLOCK; ++i) {
    float sg = (wv[i] > 0.0f) ? 1.0f : ((wv[i] < 0.0f) ? -1.0f : 0.0f);
    float deq = (scale * q[i]) * sg;   // (scale*q) then *sgn, as in reference
    o[i] = wv[i] + (deq - wv[i]);      // w + stop_gradient(deq - w)
  }

  float4 o0 = {o[0], o[1], o[2], o[3]};
  float4 o1 = {o[4], o[5], o[6], o[7]};
  float4* op = reinterpret_cast<float4*>(out) + (size_t)2 * t;
  op[0] = o0;
  op[1] = o1;
}

extern "C" void kernel_launch(void* const* d_in, const int* in_sizes, int n_in,
                              void* d_out, int out_size, void* d_ws, size_t ws_size,
                              hipStream_t stream) {
  (void)n_in; (void)d_ws; (void)ws_size; (void)out_size;
  const float* w = (const float*)d_in[0];
  float* out = (float*)d_out;
  int n = in_sizes[0];
  int nb = n / BLOCK;
  int threads = 256;
  int blocks = (nb + threads - 1) / threads;
  _IQ2XSQuantWeight_12945031430379_kernel<<<blocks, threads, 0, stream>>>(w, out, nb);
}

// Round 3
// 86.906 us; speedup vs baseline: 1.3129x; 1.3129x over previous
//
#include <hip/hip_runtime.h>

#define BLOCK 8
#define NGRID 512

// ---------------------------------------------------------------------------
// Compile-time replication of
//   np.random.RandomState(0).choice(np.array([1.0,3.0],f32), size=(512,8))
// (MT19937 legacy scalar seeding, one 32-bit draw per value, value = draw&1).
// Bit i of a pattern corresponds to element i: g[i] = bit ? 3.0f : 1.0f.
// Dedup (first occurrence) is argmax-neutral under strict-> first-max.
// ---------------------------------------------------------------------------
struct CTab {
  bool exists[256];          // pattern present among the 512 rows
  unsigned char kenc[256];   // 255 - dedup_index(pattern)  (valid iff exists)
  unsigned char pat[256];    // inverse: kenc -> pattern byte
  int nd;                    // number of distinct patterns (~222)
};

constexpr CTab make_ctab() {
  CTab t{};
  for (int i = 0; i < 256; ++i) { t.exists[i] = false; t.kenc[i] = 0; t.pat[i] = 0; }
  unsigned mt[624] = {};
  {
    unsigned s = 0u;
    for (int i = 0; i < 624; ++i) {
      mt[i] = s;
      s = 1812433253u * (s ^ (s >> 30)) + (unsigned)(i + 1);
    }
  }
  int pos = 624;
  int nd = 0;
  for (int j = 0; j < NGRID; ++j) {
    unsigned char b = 0;
    for (int i = 0; i < BLOCK; ++i) {
      if (pos == 624) {
        for (int k = 0; k < 624; ++k) {
          int k1 = (k + 1 < 624) ? k + 1 : 0;
          int k397 = (k + 397 < 624) ? k + 397 : k + 397 - 624;
          unsigned y = (mt[k] & 0x80000000u) | (mt[k1] & 0x7fffffffu);
          unsigned v = mt[k397] ^ (y >> 1);
          if (y & 1u) v ^= 0x9908b0dfu;
          mt[k] = v;
        }
        pos = 0;
      }
      unsigned y = mt[pos++];
      y ^= y >> 11;
      y ^= (y << 7) & 0x9d2c5680u;
      y ^= (y << 15) & 0xefc60000u;
      y ^= y >> 18;
      if (y & 1u) b |= (unsigned char)(1u << i);
    }
    if (!t.exists[b]) {
      t.exists[b] = true;
      t.kenc[b] = (unsigned char)(255 - nd);
      t.pat[255 - nd] = b;
      ++nd;
    }
  }
  t.nd = nd;
  return t;
}

constexpr CTab CT = make_ctab();
static_assert(CT.nd > 0 && CT.nd <= 256, "sanity");

// epilogue gather table: kenc -> pattern byte (tiny, L1-resident)
__constant__ unsigned char c_pat[256] = {};  // initialized via host? no — bake:
// NOTE: __constant__ can't be constexpr-initialized from CT directly with {} above;
// use a template trick to materialize it:
template <int... I> struct PatHolder {
  static __device__ __constant__ const unsigned char v[sizeof...(I)];
};
// simpler: just use a __device__ constexpr array — loads become s/v loads from .rodata
__device__ __constant__ const unsigned char g_pat[256] = {
#define P1(z) CT.pat[z]
#define P8(z) P1(z), P1(z+1), P1(z+2), P1(z+3), P1(z+4), P1(z+5), P1(z+6), P1(z+7)
#define P64(z) P8(z), P8(z+8), P8(z+16), P8(z+24), P8(z+32), P8(z+40), P8(z+48), P8(z+56)
    P64(0), P64(64), P64(128), P64(192)
#undef P64
#undef P8
#undef P1
};

// does any existing pattern have low `lvl` bits == prefix?
constexpr bool has_any(int lvl, int prefix) {
  for (int p = 0; p < 256; ++p) {
    if (CT.exists[p] && (p & ((1 << lvl) - 1)) == prefix) return true;
  }
  return false;
}

// ---------------------------------------------------------------------------
// DFS trie scan. At each level consume a[LVL]: child g=1 -> d+a (== fma(a,1,d)),
// child g=3 -> fma(a,3,d). Leaf: score = fl32(d*d / norm) bit-identical to the
// reference (exact pow2 scaling, or Markstein correctly-rounded division),
// then fold into the u64 (scorebits<<8 | 255-k) running max.
// ---------------------------------------------------------------------------
template <int LVL, int PREFIX>
struct Scan {
  static __device__ __forceinline__ void run(const float (&a)[BLOCK], float d,
                                             unsigned long long& best) {
    if constexpr (LVL == BLOCK) {
      constexpr int pc = __builtin_popcount(PREFIX);
      float dd = d * d;
      float sc;
      if constexpr (pc == 0)      sc = dd * 0.125f;      // /8   exact
      else if constexpr (pc == 1) sc = dd * 0.0625f;     // /16  exact
      else if constexpr (pc == 3) sc = dd * 0.03125f;    // /32  exact
      else if constexpr (pc == 7) sc = dd * 0.015625f;   // /64  exact
      else {
        constexpr float nf = (float)(8 * (1 + pc));
        constexpr float rc = 1.0f / nf;                  // RN reciprocal (compile time)
        float q0 = dd * rc;
        float r = __builtin_fmaf(-nf, q0, dd);           // exact residual
        sc = __builtin_fmaf(r, rc, q0);                  // Markstein: == fl32(dd/nf)
      }
      unsigned long long key =
          ((unsigned long long)__float_as_uint(sc) << 8) | (unsigned)CT.kenc[PREFIX];
      best = key > best ? key : best;
    } else {
      if constexpr (has_any(LVL + 1, PREFIX)) {
        float dn = d + a[LVL];                           // == fma(a,1,d)
        Scan<LVL + 1, PREFIX>::run(a, dn, best);
      }
      if constexpr (has_any(LVL + 1, PREFIX | (1 << LVL))) {
        float dn = __builtin_fmaf(a[LVL], 3.0f, d);
        Scan<LVL + 1, PREFIX | (1 << LVL)>::run(a, dn, best);
      }
    }
  }
};

__global__ __launch_bounds__(256) void _IQ2XSQuantWeight_12945031430379_kernel(
    const float* __restrict__ w, float* __restrict__ out, int nb) {
  int t = blockIdx.x * blockDim.x + threadIdx.x;
  if (t >= nb) return;

  const float4* wp = reinterpret_cast<const float4*>(w) + (size_t)2 * t;
  float4 w0 = wp[0];
  float4 w1 = wp[1];
  float wv[BLOCK] = {w0.x, w0.y, w0.z, w0.w, w1.x, w1.y, w1.z, w1.w};

  float a[BLOCK];
#pragma unroll
  for (int i = 0; i < BLOCK; ++i) a[i] = __builtin_fabsf(wv[i]);

  unsigned long long best = 0ull;
  Scan<0, 0>::run(a, 0.0f, best);

  // ---- epilogue: bit-identical to R0's (which passed at absmax 0.0078) ----
  unsigned int ke = (unsigned int)(best & 0xFFull);
  unsigned int bits = (unsigned int)g_pat[ke];   // divergent 1-byte gather, L1

  float q[BLOCK];
#pragma unroll
  for (int i = 0; i < BLOCK; ++i) q[i] = ((bits >> i) & 1u) ? 3.0f : 1.0f;

  float p[BLOCK];
#pragma unroll
  for (int i = 0; i < BLOCK; ++i) p[i] = a[i] * q[i];
  float num = ((p[0] + p[1]) + (p[2] + p[3])) + ((p[4] + p[5]) + (p[6] + p[7]));

  int popc = __popc(bits);
  float normf = (float)(8 + (popc << 3));
  float scale = num / normf;                     // IEEE CR f32 divide (once)

  float o[BLOCK];
#pragma unroll
  for (int i = 0; i < BLOCK; ++i) {
    float sg = (wv[i] > 0.0f) ? 1.0f : ((wv[i] < 0.0f) ? -1.0f : 0.0f);
    float deq = (scale * q[i]) * sg;
    o[i] = wv[i] + (deq - wv[i]);                // w + stop_gradient(deq - w)
  }

  float4 o0 = {o[0], o[1], o[2], o[3]};
  float4 o1 = {o[4], o[5], o[6], o[7]};
  float4* op = reinterpret_cast<float4*>(out) + (size_t)2 * t;
  op[0] = o0;
  op[1] = o1;
}

extern "C" void kernel_launch(void* const* d_in, const int* in_sizes, int n_in,
                              void* d_out, int out_size, void* d_ws, size_t ws_size,
                              hipStream_t stream) {
  (void)n_in; (void)d_ws; (void)ws_size; (void)out_size;
  const float* w = (const float*)d_in[0];
  float* out = (float*)d_out;
  int n = in_sizes[0];
  int nb = n / BLOCK;
  int threads = 256;
  int blocks = (nb + threads - 1) / threads;
  _IQ2XSQuantWeight_12945031430379_kernel<<<blocks, threads, 0, stream>>>(w, out, nb);
}